// Round 7
// baseline (157.485 us; speedup 1.0000x reference)
//
#include <hip/hip_runtime.h>
#include <hip/hip_bf16.h>
#include <math.h>

#define S_LEN 2048
#define NH    64        // B*H
#define TS    62        // d01/d02 outputs per tile (rows staged = 64)
#define NTILE 33        // 33*62 == 2046 == S-2 exactly
#define NDIST (NTILE * NH)   // 2112 dist blocks

typedef __attribute__((ext_vector_type(8))) short short8;
typedef __attribute__((ext_vector_type(4))) float f32x4;

__device__ __forceinline__ unsigned short f2bf(float f) {
    unsigned int u = __float_as_uint(f);
    return (unsigned short)((u + 0x7FFFu + ((u >> 16) & 1u)) >> 16);   // RNE
}

// ---------------------------------------------------------------------------
// k_prep: W (fp32, 128x128) -> Wbf (bf16). 16384 elements.
// ---------------------------------------------------------------------------
__global__ __launch_bounds__(256) void k_prep(const float* __restrict__ W,
                                              unsigned short* __restrict__ Wbf)
{
    int idx = blockIdx.x * 256 + threadIdx.x;   // 0..16383
    Wbf[idx] = f2bf(W[idx]);
}

// ---------------------------------------------------------------------------
// k_dist2: blocks 0..2111 -> dist work; blocks 2112..2623 -> (cos,sin) table.
// Dist: stage x tile bf16 in LDS; MFMA with B-frags from global Wbf (L1-hot);
// content transposed to Cs (overlay); d01/d02 norms -> global.
// LDS = 34816 B -> 4 blocks/CU.
// ---------------------------------------------------------------------------
__global__ __launch_bounds__(256) void k_dist2(const float* __restrict__ x,
                                               const unsigned short* __restrict__ Wbf,
                                               float* __restrict__ d01,
                                               float* __restrict__ d02,
                                               float2* __restrict__ tab)
{
    __shared__ char smem[34816];
    unsigned short* Xs = (unsigned short*)smem;   // 64 x 136 bf16 (17408 B)
    float*          Cs = (float*)smem;            // 128 x 68 fp32 overlay (34816 B)

    const int bid = blockIdx.x;
    const int t   = threadIdx.x;

    if (bid >= NDIST) {
        // ---- tab blocks: 512 blocks x 256 threads -> 131072 (cos,sin) ----
        int tid = (bid - NDIST) * 256 + t;        // 0 .. 2048*64-1
        int j = tid & 63;
        int s = tid >> 6;
        float base = powf(10000.f, -(float)(2 * j) * (1.f / 128.f));
        float fr = (float)s * base;
        tab[tid] = make_float2(cosf(fr), sinf(fr));
        return;
    }

    const int tile = bid >> 6;       // 0..32
    const int n    = bid & 63;       // 0..63
    const int bb   = n >> 4, hh = n & 15;
    const int s0   = tile * TS;
    const int w    = t >> 6;         // wave 0..3
    const int l    = t & 63;
    const int m    = l & 15;
    const int q    = l >> 4;

    // ---- stage x tile (64 rows x 128 cols fp32 -> bf16), coalesced float4 ----
    #pragma unroll
    for (int i = 0; i < 8; i++) {
        int idx = t + 256 * i;               // 0..2047
        int r   = idx >> 5;                  // row 0..63  (s0+r <= 2047 always)
        int c4  = idx & 31;                  // float4 index
        float4 v = *(const float4*)&x[(((size_t)(bb * S_LEN + s0 + r) * 16 + hh)) * 128 + c4 * 4];
        ushort4 p;
        p.x = f2bf(v.x); p.y = f2bf(v.y); p.z = f2bf(v.z); p.w = f2bf(v.w);
        *(ushort4*)&Xs[r * 136 + c4 * 4] = p;
    }
    __syncthreads();

    // ---- MFMA: wave w -> output rows 16w..16w+15; B frags from global Wbf ----
    f32x4 acc[8];
    #pragma unroll
    for (int ct = 0; ct < 8; ct++) acc[ct] = (f32x4){0.f, 0.f, 0.f, 0.f};

    #pragma unroll
    for (int kk = 0; kk < 4; kk++) {
        short8 a = *(const short8*)&Xs[(16 * w + m) * 136 + kk * 32 + q * 8];
        #pragma unroll
        for (int ct = 0; ct < 8; ct++) {
            short8 b = *(const short8*)&Wbf[(16 * ct + m) * 128 + kk * 32 + q * 8];
            acc[ct] = __builtin_amdgcn_mfma_f32_16x16x32_bf16(a, b, acc[ct], 0, 0, 0);
        }
    }
    __syncthreads();   // all frag reads from Xs done before overlaying Cs

    // ---- write content transposed: Cs[col*68 + row], 16B-aligned b128 writes ----
    #pragma unroll
    for (int ct = 0; ct < 8; ct++) {
        int col   = 16 * ct + m;
        int rbase = 16 * w + q * 4;
        *(f32x4*)&Cs[col * 68 + rbase] = acc[ct];
    }
    __syncthreads();

    // ---- norms: waves {0,1} -> d01 (j 0..62), waves {2,3} -> d02 (j 0..61) ----
    int which = w >> 1;                  // 0: d01, 1: d02
    int j     = (w & 1) * 32 + (l >> 1);
    int g     = l & 1;
    int lim   = which ? (TS - 1) : TS;
    bool active = (j <= lim);
    float part = 0.f;
    if (active) {
        int r1 = j, r2 = j + 1 + which;
        #pragma unroll 8
        for (int i = 0; i < 64; i++) {
            int e = g + 2 * i;
            float d = Cs[e * 68 + r1] - Cs[e * 68 + r2];
            part += d * d;
        }
    }
    part += __shfl_xor(part, 1);
    if (active && g == 0) {
        float dv = sqrtf(part);
        if (which == 0) d01[n * S_LEN + s0 + j] = dv;   // boundary dupes are bitwise-equal
        else            d02[n * S_LEN + s0 + j] = dv;
    }
}

// ---------------------------------------------------------------------------
// k_rope4: pure elementwise — one thread per float4 (2 rope pairs).
// between computed inline from global d01/d02. No LDS, no barriers.
// ---------------------------------------------------------------------------
__global__ __launch_bounds__(256) void k_rope4(const float* __restrict__ x,
                                               const float* __restrict__ d01,
                                               const float* __restrict__ d02,
                                               const float2* __restrict__ tab,
                                               float* __restrict__ out)
{
    int tid4 = blockIdx.x * 256 + threadIdx.x;   // float4 index, 0 .. 4194303
    int d4   = tid4 & 31;                        // float4 within the 128-float row
    int rem  = tid4 >> 5;                        // [b][s][h] row id
    int h    = rem & 15;
    int s    = (rem >> 4) & (S_LEN - 1);
    int b    = rem >> 15;
    int n    = b * 16 + h;

    // between (0 at s=0 and s=S-1)
    float bet = 0.f;
    if (s >= 1 && s <= S_LEN - 2) {
        int i = s - 1;
        float p  = d01[n * S_LEN + i] + d01[n * S_LEN + i + 1];
        float dd = d02[n * S_LEN + i];
        float sc = 1.f - (p - dd) / fmaxf(dd, 1e-6f);
        bet = fmaxf(sc, 0.f) * (1.f / (float)(S_LEN - 2));
    }

    float adj = (float)s + (bet - 0.5f) * 0.1f;
    adj = fminf(fmaxf(adj, 0.f), (float)(S_LEN - 1));
    float lof = floorf(adj), hif = ceilf(adj);
    float frac = adj - lof;
    int lo = (int)lof, hi = (int)hif;

    // pairs j0 = 2*d4, j1 = 2*d4+1; tab is (cos,sin) interleaved per (s,j)
    float4 tl = *(const float4*)&tab[lo * 64 + 2 * d4];
    float4 th = *(const float4*)&tab[hi * 64 + 2 * d4];
    float ci0 = (1.f - frac) * tl.x + frac * th.x;
    float si0 = (1.f - frac) * tl.y + frac * th.y;
    float ci1 = (1.f - frac) * tl.z + frac * th.z;
    float si1 = (1.f - frac) * tl.w + frac * th.w;

    float4 xv = ((const float4*)x)[tid4];
    float4 o;
    o.x = xv.x * ci0 - xv.y * si0;
    o.y = xv.y * ci0 + xv.x * si0;
    o.z = xv.z * ci1 - xv.w * si1;
    o.w = xv.w * ci1 + xv.z * si1;
    ((float4*)out)[tid4] = o;
}

// ---------------------------------------------------------------------------
extern "C" void kernel_launch(void* const* d_in, const int* in_sizes, int n_in,
                              void* d_out, int out_size, void* d_ws, size_t ws_size,
                              hipStream_t stream)
{
    const float* x = (const float*)d_in[0];
    const float* W = (const float*)d_in[1];
    // d_in[2] (bias) cancels in the d01/d02 differences -> unused
    float* out = (float*)d_out;

    float* ws = (float*)d_ws;
    float* d01 = ws;                                      // 64*2048
    float* d02 = ws + 131072;                             // 64*2048
    float2* tab = (float2*)(ws + 262144);                 // 2048*64 float2 = 1 MB
    unsigned short* Wbf = (unsigned short*)(ws + 524288); // 128*128 bf16

    k_prep <<<64, 256, 0, stream>>>(W, Wbf);
    k_dist2<<<NDIST + 512, 256, 0, stream>>>(x, Wbf, d01, d02, tab);
    k_rope4<<<16384, 256, 0, stream>>>(x, d01, d02, tab, out);
}